// Round 12
// baseline (210.063 us; speedup 1.0000x reference)
//
#include <hip/hip_runtime.h>
#include <stdint.h>

typedef uint16_t u16;
typedef __bf16 bf16x8 __attribute__((ext_vector_type(8)));
typedef float   f32x4 __attribute__((ext_vector_type(4)));
typedef uint16_t u16x2 __attribute__((ext_vector_type(2)));
typedef uint16_t u16x4 __attribute__((ext_vector_type(4)));
typedef uint16_t u16x8 __attribute__((ext_vector_type(8)));
typedef float   f32x4g __attribute__((ext_vector_type(4)));

#define DEV __device__ __forceinline__

DEV u16 f2bf(float f) {                    // native cvt: compiler pairs into v_cvt_pk_bf16_f32
  __bf16 h = (__bf16)f;
  return __builtin_bit_cast(u16, h);
}
DEV float bf2f(u16 u) {
  union { uint32_t u; float f; } v; v.u = ((uint32_t)u) << 16;
  return v.f;
}
DEV float exp2fast(float x) {              // bare v_exp_f32 (2^x)
  float r; asm("v_exp_f32 %0, %1" : "=v"(r) : "v"(x)); return r;
}

// async global->LDS, 16B per lane; LDS dest = wave-uniform base + lane*16 (linear)
DEV void gload_lds16(const u16* g, u16* l) {
  __builtin_amdgcn_global_load_lds((const __attribute__((address_space(1))) void*)g,
                                   (__attribute__((address_space(3))) void*)l,
                                   16, 0, 0);
}

// ---------------- RoPE cos/sin table: 2048 x 32 float2 (512 KB, L2-resident) ----------------
__global__ void sctab_kernel(float2* __restrict__ tab) {
  const int idx = blockIdx.x * 256 + threadIdx.x;   // 65536
  const int s = idx >> 5, i = idx & 31;
  const float invf = (float)exp2(-2.0 * (double)i / 64.0 * 13.287712379549449);  // log2(10000)
  float sn, cs;
  sincosf((float)s * invf, &sn, &cs);
  tab[idx] = make_float2(cs, sn);
}

// ---------------- fp32 -> bf16 convert: all 3 inputs in one launch ----------------
__global__ void cvt3_kernel(const float* __restrict__ a, u16* __restrict__ da,
                            const float* __restrict__ b, u16* __restrict__ db,
                            const float* __restrict__ c, u16* __restrict__ dc) {
  int i = blockIdx.x * 256 + threadIdx.x;          // 3145728 float4s total
  const float* s; u16* d; int off;
  if (i < 2097152)      { s = a; d = da; off = i; }
  else if (i < 2883584) { s = b; d = db; off = i - 2097152; }
  else                  { s = c; d = dc; off = i - 2883584; }
  f32x4g v = ((const f32x4g*)s)[off];
  u16 tmp[4] = {f2bf(v[0]), f2bf(v[1]), f2bf(v[2]), f2bf(v[3])};
  *(uint64_t*)(d + (size_t)off * 4) = *(const uint64_t*)tmp;
}

// ---------------- fused QKV GEMM: qkv = x * wqkv^T with RoPE + head-major + V-transpose epilogue ----------------
__global__ __launch_bounds__(256) void gemm_qkv(const u16* __restrict__ A,
                                                const u16* __restrict__ B,
                                                const float2* __restrict__ tab,
                                                u16* __restrict__ Qh,
                                                u16* __restrict__ Kh,
                                                u16* __restrict__ Vt) {
  constexpr int K = 1024;
  constexpr int BK = 32;
  __shared__ __align__(16) u16 SM[4][128 * BK];   // [0..1]=A dbuf, [2..3]=B dbuf; epilogue reuses as f32
  const int t = threadIdx.x;
  const int w = t >> 6, l = t & 63;
  const int l4 = l >> 4, l15 = l & 15;

  // XCD swizzle (nwg = 1536, %8==0)
  const int nbx = gridDim.x;
  const int nwg = gridDim.x * gridDim.y;
  const int orig = blockIdx.y * nbx + blockIdx.x;
  const int wgid = (orig & 7) * (nwg >> 3) + (orig >> 3);
  const int bm = (wgid / nbx) * 128, bn = (wgid % nbx) * 128;

  const int wr = (w >> 1) * 64, wc = (w & 1) * 64;

  const int srow = w * 32 + (l >> 2);
  const int scol = (l & 3) * 8;
  const u16* gA = A + (size_t)(bm + srow) * K + scol;
  const u16* gB = B + (size_t)(bn + srow) * K + scol;

  f32x4 acc[4][4];
#pragma unroll
  for (int m = 0; m < 4; ++m)
#pragma unroll
    for (int n = 0; n < 4; ++n) acc[m][n] = f32x4{0.f, 0.f, 0.f, 0.f};

  const int nkt = K / BK;

  auto stage = [&](int kt, int buf) {
    const u16* a0 = gA + (size_t)kt * BK;
    const u16* b0 = gB + (size_t)kt * BK;
    gload_lds16(a0,                  &SM[buf][(w * 32) * BK]);
    gload_lds16(a0 + (size_t)16 * K, &SM[buf][(w * 32 + 16) * BK]);
    gload_lds16(b0,                  &SM[2 + buf][(w * 32) * BK]);
    gload_lds16(b0 + (size_t)16 * K, &SM[2 + buf][(w * 32 + 16) * BK]);
  };

  stage(0, 0);
  __syncthreads();
  for (int kt = 0; kt < nkt; ++kt) {
    const int buf = kt & 1;
    if (kt + 1 < nkt) stage(kt + 1, buf ^ 1);
    bf16x8 af[4], bfr[4];
#pragma unroll
    for (int m = 0; m < 4; ++m) af[m]  = *(const bf16x8*)&SM[buf][(wr + m * 16 + l15) * BK + l4 * 8];
#pragma unroll
    for (int n = 0; n < 4; ++n) bfr[n] = *(const bf16x8*)&SM[2 + buf][(wc + n * 16 + l15) * BK + l4 * 8];
#pragma unroll
    for (int m = 0; m < 4; ++m)
#pragma unroll
      for (int n = 0; n < 4; ++n)
        acc[m][n] = __builtin_amdgcn_mfma_f32_16x16x32_bf16(af[m], bfr[n], acc[m][n], 0, 0, 0);
    __syncthreads();
  }

  // ---- LDS-bounce epilogue: 32-row x 128-col f32 tile per m-chunk ----
  constexpr int LDW = 132;                 // f32 row stride (16B-aligned rows, bank-spread)
  float* Lf = (float*)SM;                  // 32*132*4 = 16.9 KB of the 32 KB
  const int part = bn >> 10;               // 0=q 1=k 2=v (block-uniform; 1024%128==0)
  const int cb = bn & 1023;
  const float qs = (part == 0) ? 0.18033688011112042f : 1.0f;   // 0.125*log2(e) folded into q
  u16* const Out = (part == 0) ? Qh : Kh;
  const int lrbase = (w >> 1) * 16 + l4 * 4;
  const int lcbase = (w & 1) * 64 + l15;

#pragma unroll
  for (int m = 0; m < 4; ++m) {
    if (m) __syncthreads();                // prev read phase done
#pragma unroll
    for (int n = 0; n < 4; ++n)
#pragma unroll
      for (int r = 0; r < 4; ++r)
        Lf[(lrbase + r) * LDW + lcbase + n * 16] = acc[m][n][r];
    __syncthreads();                       // tile ready

    if (part != 2) {
      // q/k: one output row-segment of 16 consecutive d per thread
      const int rr = t >> 3;               // 0..31 LDS row
      const int c0 = (t & 7) * 16;         // 16-col chunk (within one head)
      const int grow = bm + (rr >> 4) * 64 + m * 16 + (rr & 15);
      const int bb = grow >> 11, ss = grow & 2047;
      float f[16];
#pragma unroll
      for (int j = 0; j < 4; ++j)
        *(f32x4g*)&f[j * 4] = *(const f32x4g*)&Lf[rr * LDW + c0 + j * 4];
      const int cc0 = cb + c0;
      const int hh = cc0 >> 6, dd0 = cc0 & 63;
      const float2* tp = &tab[(size_t)ss * 32 + (dd0 >> 1)];
      u16 ob[16];
#pragma unroll
      for (int jp = 0; jp < 8; ++jp) {
        const float2 cs2 = tp[jp];
        ob[2 * jp]     = f2bf((f[2 * jp] * cs2.x - f[2 * jp + 1] * cs2.y) * qs);
        ob[2 * jp + 1] = f2bf((f[2 * jp] * cs2.y + f[2 * jp + 1] * cs2.x) * qs);
      }
      u16* op = Out + ((size_t)(bb * 16 + hh) * 2048 + ss) * 64 + dd0;
      *(u16x8*)op       = *(u16x8*)ob;
      *(u16x8*)(op + 8) = *(u16x8*)(ob + 8);
    } else {
      // v: one LDS column (16 consecutive s) per thread -> Vt[(b,h,d)][s]
      const int c = t >> 1, half = t & 1;
      const int cc = cb + c, hh = cc >> 6, dd = cc & 63;
      const int g0 = bm + half * 64 + m * 16;
      const int bb = g0 >> 11, ss0 = g0 & 2047;
      u16 ob[16];
#pragma unroll
      for (int j = 0; j < 16; ++j)
        ob[j] = f2bf(Lf[(half * 16 + j) * LDW + c]);
      u16* vp = Vt + ((size_t)(bb * 16 + hh) * 64 + dd) * 2048 + ss0;
      *(u16x8*)vp       = *(u16x8*)ob;
      *(u16x8*)(vp + 8) = *(u16x8*)(ob + 8);
    }
  }
}

// ---------------- GEMM: C(MxN) = A(MxK) * B(NxK)^T, bf16 in, fp32 acc (gemm2) ----------------
template<bool OUT_BF16>
__global__ __launch_bounds__(256) void gemm_bt(const u16* __restrict__ A,
                                               const u16* __restrict__ B,
                                               void* __restrict__ Cv,
                                               int M, int N, int K) {
  constexpr int BK = 32;
  __shared__ __align__(16) u16 As[2][128 * BK];
  __shared__ __align__(16) u16 Bs[2][128 * BK];
  const int t = threadIdx.x;
  const int w = t >> 6, l = t & 63;
  const int l4 = l >> 4, l15 = l & 15;

  const int nbx = gridDim.x;
  const int nwg = gridDim.x * gridDim.y;
  const int orig = blockIdx.y * nbx + blockIdx.x;
  const int wgid = (orig & 7) * (nwg >> 3) + (orig >> 3);
  const int bm = (wgid / nbx) * 128, bn = (wgid % nbx) * 128;

  const int wr = (w >> 1) * 64, wc = (w & 1) * 64;

  const int srow = w * 32 + (l >> 2);
  const int scol = (l & 3) * 8;
  const u16* gA = A + (size_t)(bm + srow) * K + scol;
  const u16* gB = B + (size_t)(bn + srow) * K + scol;

  f32x4 acc[4][4];
#pragma unroll
  for (int m = 0; m < 4; ++m)
#pragma unroll
    for (int n = 0; n < 4; ++n) acc[m][n] = f32x4{0.f, 0.f, 0.f, 0.f};

  const int nkt = K / BK;

  auto stage = [&](int kt, int buf) {
    const u16* a0 = gA + (size_t)kt * BK;
    const u16* b0 = gB + (size_t)kt * BK;
    gload_lds16(a0,                  &As[buf][(w * 32) * BK]);
    gload_lds16(a0 + (size_t)16 * K, &As[buf][(w * 32 + 16) * BK]);
    gload_lds16(b0,                  &Bs[buf][(w * 32) * BK]);
    gload_lds16(b0 + (size_t)16 * K, &Bs[buf][(w * 32 + 16) * BK]);
  };

  stage(0, 0);
  __syncthreads();
  for (int kt = 0; kt < nkt; ++kt) {
    const int buf = kt & 1;
    if (kt + 1 < nkt) stage(kt + 1, buf ^ 1);
    bf16x8 af[4], bfr[4];
#pragma unroll
    for (int m = 0; m < 4; ++m) af[m]  = *(const bf16x8*)&As[buf][(wr + m * 16 + l15) * BK + l4 * 8];
#pragma unroll
    for (int n = 0; n < 4; ++n) bfr[n] = *(const bf16x8*)&Bs[buf][(wc + n * 16 + l15) * BK + l4 * 8];
#pragma unroll
    for (int m = 0; m < 4; ++m)
#pragma unroll
      for (int n = 0; n < 4; ++n)
        acc[m][n] = __builtin_amdgcn_mfma_f32_16x16x32_bf16(af[m], bfr[n], acc[m][n], 0, 0, 0);
    __syncthreads();
  }

#pragma unroll
  for (int m = 0; m < 4; ++m) {
    const int row0 = bm + wr + m * 16 + l4 * 4;
#pragma unroll
    for (int n = 0; n < 4; ++n) {
      const int col = bn + wc + n * 16 + l15;
#pragma unroll
      for (int r = 0; r < 4; ++r) {
        if (OUT_BF16) ((u16*)Cv)[(size_t)(row0 + r) * N + col] = f2bf(acc[m][n][r]);
        else          ((float*)Cv)[(size_t)(row0 + r) * N + col] = acc[m][n][r];
      }
    }
  }
}

// ---------------- causal flash attention: 128-row blocks, 2 same-segment frags per wave ----------------
// Block = 128 contiguous q-rows (segment s in 0..15, nkv = 2s+2 kv-tiles); wave w owns
// rows w*32 + {0,16} as 2 frags. Per-iter body = R6's proven 2-SCORE + 2-PV (80 VGPR).
// Total block-iters 17408 (-48% vs 64-row blocks): staging+barrier overhead halves.
// Frags run unconditionally; causal mask zeroes inactive frags (exp2(-1e30)=0).
// Order-robust balance: s-map pairs (15,0),(14,1).. so any consecutive-4 OR stride-256
// block group sums to 68 iters. Grid 1024 = exactly 4 blocks/CU (LDS 36.9KB).
__global__ __launch_bounds__(256) void attn_kernel(const u16* __restrict__ Qh,
                                                   const u16* __restrict__ Kh,
                                                   const u16* __restrict__ Vt,
                                                   u16* __restrict__ Y) {
  __shared__ __align__(16) u16 Ks[64][72];
  __shared__ __align__(16) u16 Vs[64][72];
  __shared__ __align__(16) u16 Ps[4][32][72];
  const int t = threadIdx.x, w = t >> 6, l = t & 63;
  const int l4 = l >> 4, l15 = l & 15;
  const int bid = blockIdx.x;                   // 1024 linear
  const int sidx = (bid + (bid >> 8)) & 15;     // balanced under both dispatch orders
  const int s = (sidx & 1) ? (sidx >> 1) : (15 - (sidx >> 1));
  const int bh = bid >> 4;                      // 0..63
  const int b = bh >> 4, h = bh & 15;
  const int qb0 = s * 128 + w * 32;             // frag 0
  const int qb1 = qb0 + 16;                     // frag 1
  const u16* Qb = Qh + (size_t)bh * 2048 * 64;
  const u16* Kb = Kh + (size_t)bh * 2048 * 64;
  const u16* Vb = Vt + (size_t)bh * 64 * 2048;

  bf16x8 qf[2][2];
  {
    const int qb[2] = {qb0, qb1};
#pragma unroll
    for (int m = 0; m < 2; ++m)
#pragma unroll
      for (int ks = 0; ks < 2; ++ks)
        qf[m][ks] = *(const bf16x8*)(Qb + (size_t)(qb[m] + l15) * 64 + ks * 32 + l4 * 8);
  }

  f32x4 o[2][4];
#pragma unroll
  for (int m = 0; m < 2; ++m)
#pragma unroll
    for (int nd = 0; nd < 4; ++nd) o[m][nd] = f32x4{0.f, 0.f, 0.f, 0.f};
  float lsum[2] = {0.f, 0.f};               // per-lane partial row sums (reduced in epilogue)

  const int sr = t >> 3;          // 0..31
  const int scol = (t & 7) * 8;   // 0..56
  const int nkv = 2 * s + 2;

  // prologue: tile 0 -> regs
  u16x8 rk0 = *(const u16x8*)(Kb + (size_t)sr * 64 + scol);
  u16x8 rk1 = *(const u16x8*)(Kb + (size_t)(sr + 32) * 64 + scol);
  u16x8 rv0 = *(const u16x8*)(Vb + (size_t)sr * 2048 + scol);
  u16x8 rv1 = *(const u16x8*)(Vb + (size_t)(sr + 32) * 2048 + scol);

  for (int kv = 0; kv < nkv; ++kv) {
    const int kv0 = kv * 64;
    __syncthreads();                       // prev compute done reading LDS
    *(u16x8*)&Ks[sr][scol]      = rk0;
    *(u16x8*)&Ks[sr + 32][scol] = rk1;
    *(u16x8*)&Vs[sr][scol]      = rv0;     // Vs[d][key]
    *(u16x8*)&Vs[sr + 32][scol] = rv1;
    __syncthreads();
    if (kv + 1 < nkv) {                    // next tile -> regs (1-iter-early prefetch, T14)
      const int n0 = kv0 + 64;
      rk0 = *(const u16x8*)(Kb + (size_t)(n0 + sr) * 64 + scol);
      rk1 = *(const u16x8*)(Kb + (size_t)(n0 + sr + 32) * 64 + scol);
      rv0 = *(const u16x8*)(Vb + (size_t)sr * 2048 + n0 + scol);
      rv1 = *(const u16x8*)(Vb + (size_t)(sr + 32) * 2048 + n0 + scol);
    }

    auto SCORE = [&](int m, int qbm) {
      f32x4 sfr[4];
      __builtin_amdgcn_s_setprio(1);
#pragma unroll
      for (int n = 0; n < 4; ++n) {
        bf16x8 kf0 = *(const bf16x8*)&Ks[n * 16 + l15][l4 * 8];
        bf16x8 kf1 = *(const bf16x8*)&Ks[n * 16 + l15][32 + l4 * 8];
        f32x4 a = f32x4{0.f, 0.f, 0.f, 0.f};
        a = __builtin_amdgcn_mfma_f32_16x16x32_bf16(kf0, qf[m][0], a, 0, 0, 0);
        a = __builtin_amdgcn_mfma_f32_16x16x32_bf16(kf1, qf[m][1], a, 0, 0, 0);
        sfr[n] = a;
      }
      __builtin_amdgcn_s_setprio(0);
      if (kv0 + 63 > qbm) {                // diagonal or beyond: mask key > q
        const int q = qbm + l15;
#pragma unroll
        for (int n = 0; n < 4; ++n)
#pragma unroll
          for (int r = 0; r < 4; ++r)
            if (kv0 + n * 16 + l4 * 4 + r > q) sfr[n][r] = -1e30f;
      }
      float rs = 0.f;
#pragma unroll
      for (int n = 0; n < 4; ++n) {
#pragma unroll
        for (int r = 0; r < 4; ++r) {
          const float pv = exp2fast(sfr[n][r]);   // no max shift (bounded log2 scores)
          sfr[n][r] = pv; rs += pv;
        }
        u16x4 pk = {f2bf(sfr[n][0]), f2bf(sfr[n][1]), f2bf(sfr[n][2]), f2bf(sfr[n][3])};
        *(u16x4*)&Ps[w][m * 16 + l15][n * 16 + l4 * 4] = pk;
      }
      lsum[m] += rs;
    };

    SCORE(1, qb1);
    SCORE(0, qb0);

    bf16x8 vfr[4][2];
#pragma unroll
    for (int nd = 0; nd < 4; ++nd) {
      vfr[nd][0] = *(const bf16x8*)&Vs[nd * 16 + l15][l4 * 8];
      vfr[nd][1] = *(const bf16x8*)&Vs[nd * 16 + l15][32 + l4 * 8];
    }

    auto PV = [&](int m) {
      bf16x8 pf0 = *(const bf16x8*)&Ps[w][m * 16 + l15][l4 * 8];
      bf16x8 pf1 = *(const bf16x8*)&Ps[w][m * 16 + l15][32 + l4 * 8];
      __builtin_amdgcn_s_setprio(1);
#pragma unroll
      for (int nd = 0; nd < 4; ++nd) {
        o[m][nd] = __builtin_amdgcn_mfma_f32_16x16x32_bf16(pf0, vfr[nd][0], o[m][nd], 0, 0, 0);
        o[m][nd] = __builtin_amdgcn_mfma_f32_16x16x32_bf16(pf1, vfr[nd][1], o[m][nd], 0, 0, 0);
      }
      __builtin_amdgcn_s_setprio(0);
    };
    PV(1);
    PV(0);
  }

  // epilogue: reduce lsum across the 4 lane-groups, broadcast 1/l into o-layout, write Y
  const int qb[2] = {qb0, qb1};
#pragma unroll
  for (int m = 0; m < 2; ++m) {
    lsum[m] += __shfl_xor(lsum[m], 16);
    lsum[m] += __shfl_xor(lsum[m], 32);
    const float li = 1.0f / lsum[m];
    float lb[4];
#pragma unroll
    for (int r = 0; r < 4; ++r) lb[r] = __shfl(li, (l & 48) | (l4 * 4 + r));
#pragma unroll
    for (int r = 0; r < 4; ++r) {
      const size_t row = (size_t)b * 2048 + qb[m] + l4 * 4 + r;
#pragma unroll
      for (int nd = 0; nd < 4; ++nd)
        Y[row * 1024 + h * 64 + nd * 16 + l15] = f2bf(o[m][nd][r] * lb[r]);
    }
  }
}

extern "C" void kernel_launch(void* const* d_in, const int* in_sizes, int n_in,
                              void* d_out, int out_size, void* d_ws, size_t ws_size,
                              hipStream_t stream) {
  const float* x    = (const float*)d_in[0];   // 4*2048*1024
  const float* wqkv = (const float*)d_in[1];   // 3072*1024
  const float* wout = (const float*)d_in[2];   // 1024*1024
  float* out = (float*)d_out;                  // 8192*1024 fp32
  char* ws = (char*)d_ws;

  u16* x_bf    = (u16*)(ws);               // 16 MiB (reused as Y after gemm_qkv)
  u16* Y       = x_bf;
  u16* wqkv_bf = (u16*)(ws + 16777216);    // 6 MiB
  u16* wout_bf = (u16*)(ws + 23068672);    // 2 MiB
  float2* tab  = (float2*)(ws + 25165824); // 512 KiB (rope cos/sin table)
  u16* Qh      = (u16*)(ws + 75497472);    // 16 MiB
  u16* Kh      = (u16*)(ws + 92274688);    // 16 MiB
  u16* Vt      = (u16*)(ws + 109051904);   // 16 MiB

  sctab_kernel<<<256, 256, 0, stream>>>(tab);
  cvt3_kernel<<<12288, 256, 0, stream>>>(x, x_bf, wqkv, wqkv_bf, wout, wout_bf);
  gemm_qkv<<<dim3(24, 64), 256, 0, stream>>>(x_bf, wqkv_bf, tab, Qh, Kh, Vt);
  attn_kernel<<<1024, 256, 0, stream>>>(Qh, Kh, Vt, Y);
  gemm_bt<false><<<dim3(8, 64), 256, 0, stream>>>(Y, wout_bf, out, 8192, 1024, 1024);
}

// Round 13
// 188.257 us; speedup vs baseline: 1.1158x; 1.1158x over previous
//
#include <hip/hip_runtime.h>
#include <stdint.h>

typedef uint16_t u16;
typedef __bf16 bf16x8 __attribute__((ext_vector_type(8)));
typedef float   f32x4 __attribute__((ext_vector_type(4)));
typedef uint16_t u16x2 __attribute__((ext_vector_type(2)));
typedef uint16_t u16x4 __attribute__((ext_vector_type(4)));
typedef uint16_t u16x8 __attribute__((ext_vector_type(8)));
typedef float   f32x4g __attribute__((ext_vector_type(4)));

#define DEV __device__ __forceinline__

DEV u16 f2bf(float f) {                    // native cvt: compiler pairs into v_cvt_pk_bf16_f32
  __bf16 h = (__bf16)f;
  return __builtin_bit_cast(u16, h);
}
DEV float bf2f(u16 u) {
  union { uint32_t u; float f; } v; v.u = ((uint32_t)u) << 16;
  return v.f;
}
DEV float exp2fast(float x) {              // bare v_exp_f32 (2^x)
  float r; asm("v_exp_f32 %0, %1" : "=v"(r) : "v"(x)); return r;
}

// async global->LDS, 16B per lane; LDS dest = wave-uniform base + lane*16 (linear)
DEV void gload_lds16(const u16* g, u16* l) {
  __builtin_amdgcn_global_load_lds((const __attribute__((address_space(1))) void*)g,
                                   (__attribute__((address_space(3))) void*)l,
                                   16, 0, 0);
}

// ---------------- fp32 -> bf16 convert (3 inputs) + RoPE table, one launch ----------------
__global__ void cvt3_kernel(const float* __restrict__ a, u16* __restrict__ da,
                            const float* __restrict__ b, u16* __restrict__ db,
                            const float* __restrict__ c, u16* __restrict__ dc,
                            float2* __restrict__ tab) {
  int i = blockIdx.x * 256 + threadIdx.x;          // 3145728 cvt float4s + 65536 tab entries
  if (i >= 3145728) {                              // RoPE cos/sin table (block-uniform branch)
    const int idx = i - 3145728;                   // 2048 x 32 float2 (512 KB, L2-resident)
    const int s = idx >> 5, fi = idx & 31;
    const float invf = (float)exp2(-2.0 * (double)fi / 64.0 * 13.287712379549449);  // log2(10000)
    float sn, cs;
    sincosf((float)s * invf, &sn, &cs);
    tab[idx] = make_float2(cs, sn);
    return;
  }
  const float* s; u16* d; int off;
  if (i < 2097152)      { s = a; d = da; off = i; }
  else if (i < 2883584) { s = b; d = db; off = i - 2097152; }
  else                  { s = c; d = dc; off = i - 2883584; }
  f32x4g v = ((const f32x4g*)s)[off];
  u16 tmp[4] = {f2bf(v[0]), f2bf(v[1]), f2bf(v[2]), f2bf(v[3])};
  *(uint64_t*)(d + (size_t)off * 4) = *(const uint64_t*)tmp;
}

// ---------------- fused QKV GEMM: qkv = x * wqkv^T with RoPE + head-major + V-transpose epilogue ----------------
__global__ __launch_bounds__(256) void gemm_qkv(const u16* __restrict__ A,
                                                const u16* __restrict__ B,
                                                const float2* __restrict__ tab,
                                                u16* __restrict__ Qh,
                                                u16* __restrict__ Kh,
                                                u16* __restrict__ Vt) {
  constexpr int K = 1024;
  constexpr int BK = 32;
  __shared__ __align__(16) u16 SM[4][128 * BK];   // [0..1]=A dbuf, [2..3]=B dbuf; epilogue reuses as f32
  const int t = threadIdx.x;
  const int w = t >> 6, l = t & 63;
  const int l4 = l >> 4, l15 = l & 15;

  // XCD swizzle (nwg = 1536, %8==0)
  const int nbx = gridDim.x;
  const int nwg = gridDim.x * gridDim.y;
  const int orig = blockIdx.y * nbx + blockIdx.x;
  const int wgid = (orig & 7) * (nwg >> 3) + (orig >> 3);
  const int bm = (wgid / nbx) * 128, bn = (wgid % nbx) * 128;

  const int wr = (w >> 1) * 64, wc = (w & 1) * 64;

  const int srow = w * 32 + (l >> 2);
  const int scol = (l & 3) * 8;
  const u16* gA = A + (size_t)(bm + srow) * K + scol;
  const u16* gB = B + (size_t)(bn + srow) * K + scol;

  f32x4 acc[4][4];
#pragma unroll
  for (int m = 0; m < 4; ++m)
#pragma unroll
    for (int n = 0; n < 4; ++n) acc[m][n] = f32x4{0.f, 0.f, 0.f, 0.f};

  const int nkt = K / BK;

  auto stage = [&](int kt, int buf) {
    const u16* a0 = gA + (size_t)kt * BK;
    const u16* b0 = gB + (size_t)kt * BK;
    gload_lds16(a0,                  &SM[buf][(w * 32) * BK]);
    gload_lds16(a0 + (size_t)16 * K, &SM[buf][(w * 32 + 16) * BK]);
    gload_lds16(b0,                  &SM[2 + buf][(w * 32) * BK]);
    gload_lds16(b0 + (size_t)16 * K, &SM[2 + buf][(w * 32 + 16) * BK]);
  };

  stage(0, 0);
  __syncthreads();
  for (int kt = 0; kt < nkt; ++kt) {
    const int buf = kt & 1;
    if (kt + 1 < nkt) stage(kt + 1, buf ^ 1);
    bf16x8 af[4], bfr[4];
#pragma unroll
    for (int m = 0; m < 4; ++m) af[m]  = *(const bf16x8*)&SM[buf][(wr + m * 16 + l15) * BK + l4 * 8];
#pragma unroll
    for (int n = 0; n < 4; ++n) bfr[n] = *(const bf16x8*)&SM[2 + buf][(wc + n * 16 + l15) * BK + l4 * 8];
#pragma unroll
    for (int m = 0; m < 4; ++m)
#pragma unroll
      for (int n = 0; n < 4; ++n)
        acc[m][n] = __builtin_amdgcn_mfma_f32_16x16x32_bf16(af[m], bfr[n], acc[m][n], 0, 0, 0);
    __syncthreads();
  }

  // ---- LDS-bounce epilogue: 32-row x 128-col f32 tile per m-chunk ----
  constexpr int LDW = 132;                 // f32 row stride (16B-aligned rows, bank-spread)
  float* Lf = (float*)SM;                  // 32*132*4 = 16.9 KB of the 32 KB
  const int part = bn >> 10;               // 0=q 1=k 2=v (block-uniform; 1024%128==0)
  const int cb = bn & 1023;
  const float qs = (part == 0) ? 0.18033688011112042f : 1.0f;   // 0.125*log2(e) folded into q
  u16* const Out = (part == 0) ? Qh : Kh;
  const int lrbase = (w >> 1) * 16 + l4 * 4;
  const int lcbase = (w & 1) * 64 + l15;

#pragma unroll
  for (int m = 0; m < 4; ++m) {
    if (m) __syncthreads();                // prev read phase done
#pragma unroll
    for (int n = 0; n < 4; ++n)
#pragma unroll
      for (int r = 0; r < 4; ++r)
        Lf[(lrbase + r) * LDW + lcbase + n * 16] = acc[m][n][r];
    __syncthreads();                       // tile ready

    if (part != 2) {
      // q/k: one output row-segment of 16 consecutive d per thread
      const int rr = t >> 3;               // 0..31 LDS row
      const int c0 = (t & 7) * 16;         // 16-col chunk (within one head)
      const int grow = bm + (rr >> 4) * 64 + m * 16 + (rr & 15);
      const int bb = grow >> 11, ss = grow & 2047;
      float f[16];
#pragma unroll
      for (int j = 0; j < 4; ++j)
        *(f32x4g*)&f[j * 4] = *(const f32x4g*)&Lf[rr * LDW + c0 + j * 4];
      const int cc0 = cb + c0;
      const int hh = cc0 >> 6, dd0 = cc0 & 63;
      const float2* tp = &tab[(size_t)ss * 32 + (dd0 >> 1)];
      u16 ob[16];
#pragma unroll
      for (int jp = 0; jp < 8; ++jp) {
        const float2 cs2 = tp[jp];
        ob[2 * jp]     = f2bf((f[2 * jp] * cs2.x - f[2 * jp + 1] * cs2.y) * qs);
        ob[2 * jp + 1] = f2bf((f[2 * jp] * cs2.y + f[2 * jp + 1] * cs2.x) * qs);
      }
      u16* op = Out + ((size_t)(bb * 16 + hh) * 2048 + ss) * 64 + dd0;
      *(u16x8*)op       = *(u16x8*)ob;
      *(u16x8*)(op + 8) = *(u16x8*)(ob + 8);
    } else {
      // v: one LDS column (16 consecutive s) per thread -> Vt[(b,h,d)][s]
      const int c = t >> 1, half = t & 1;
      const int cc = cb + c, hh = cc >> 6, dd = cc & 63;
      const int g0 = bm + half * 64 + m * 16;
      const int bb = g0 >> 11, ss0 = g0 & 2047;
      u16 ob[16];
#pragma unroll
      for (int j = 0; j < 16; ++j)
        ob[j] = f2bf(Lf[(half * 16 + j) * LDW + c]);
      u16* vp = Vt + ((size_t)(bb * 16 + hh) * 64 + dd) * 2048 + ss0;
      *(u16x8*)vp       = *(u16x8*)ob;
      *(u16x8*)(vp + 8) = *(u16x8*)(ob + 8);
    }
  }
}

// ---------------- GEMM: C(MxN) = A(MxK) * B(NxK)^T, bf16 in, fp32 acc (gemm2) ----------------
template<bool OUT_BF16>
__global__ __launch_bounds__(256) void gemm_bt(const u16* __restrict__ A,
                                               const u16* __restrict__ B,
                                               void* __restrict__ Cv,
                                               int M, int N, int K) {
  constexpr int BK = 32;
  __shared__ __align__(16) u16 As[2][128 * BK];
  __shared__ __align__(16) u16 Bs[2][128 * BK];
  const int t = threadIdx.x;
  const int w = t >> 6, l = t & 63;
  const int l4 = l >> 4, l15 = l & 15;

  const int nbx = gridDim.x;
  const int nwg = gridDim.x * gridDim.y;
  const int orig = blockIdx.y * nbx + blockIdx.x;
  const int wgid = (orig & 7) * (nwg >> 3) + (orig >> 3);
  const int bm = (wgid / nbx) * 128, bn = (wgid % nbx) * 128;

  const int wr = (w >> 1) * 64, wc = (w & 1) * 64;

  const int srow = w * 32 + (l >> 2);
  const int scol = (l & 3) * 8;
  const u16* gA = A + (size_t)(bm + srow) * K + scol;
  const u16* gB = B + (size_t)(bn + srow) * K + scol;

  f32x4 acc[4][4];
#pragma unroll
  for (int m = 0; m < 4; ++m)
#pragma unroll
    for (int n = 0; n < 4; ++n) acc[m][n] = f32x4{0.f, 0.f, 0.f, 0.f};

  const int nkt = K / BK;

  auto stage = [&](int kt, int buf) {
    const u16* a0 = gA + (size_t)kt * BK;
    const u16* b0 = gB + (size_t)kt * BK;
    gload_lds16(a0,                  &As[buf][(w * 32) * BK]);
    gload_lds16(a0 + (size_t)16 * K, &As[buf][(w * 32 + 16) * BK]);
    gload_lds16(b0,                  &Bs[buf][(w * 32) * BK]);
    gload_lds16(b0 + (size_t)16 * K, &Bs[buf][(w * 32 + 16) * BK]);
  };

  stage(0, 0);
  __syncthreads();
  for (int kt = 0; kt < nkt; ++kt) {
    const int buf = kt & 1;
    if (kt + 1 < nkt) stage(kt + 1, buf ^ 1);
    bf16x8 af[4], bfr[4];
#pragma unroll
    for (int m = 0; m < 4; ++m) af[m]  = *(const bf16x8*)&As[buf][(wr + m * 16 + l15) * BK + l4 * 8];
#pragma unroll
    for (int n = 0; n < 4; ++n) bfr[n] = *(const bf16x8*)&Bs[buf][(wc + n * 16 + l15) * BK + l4 * 8];
#pragma unroll
    for (int m = 0; m < 4; ++m)
#pragma unroll
      for (int n = 0; n < 4; ++n)
        acc[m][n] = __builtin_amdgcn_mfma_f32_16x16x32_bf16(af[m], bfr[n], acc[m][n], 0, 0, 0);
    __syncthreads();
  }

#pragma unroll
  for (int m = 0; m < 4; ++m) {
    const int row0 = bm + wr + m * 16 + l4 * 4;
#pragma unroll
    for (int n = 0; n < 4; ++n) {
      const int col = bn + wc + n * 16 + l15;
#pragma unroll
      for (int r = 0; r < 4; ++r) {
        if (OUT_BF16) ((u16*)Cv)[(size_t)(row0 + r) * N + col] = f2bf(acc[m][n][r]);
        else          ((float*)Cv)[(size_t)(row0 + r) * N + col] = acc[m][n][r];
      }
    }
  }
}

// ---------------- causal flash attention: un-paired, oversubscribed, longest-first ----------------
// R10 structure (measured best: 83us, VGPR 48). Deltas: LDS stride 72->68 (34 words =
// 2 mod 32 -> all b128 reads and b64 writes <=2-way bank aliasing, was 4-way at 72;
// LDS 27.6->25.5KB -> 6 blocks/CU) and launch_bounds(256,8) pinning VGPR<=64 so LDS
// is the only occupancy limiter.
__global__ __launch_bounds__(256, 8) void attn_kernel(const u16* __restrict__ Qh,
                                                      const u16* __restrict__ Kh,
                                                      const u16* __restrict__ Vt,
                                                      u16* __restrict__ Y) {
  __shared__ __align__(16) u16 Ks[64][68];
  __shared__ __align__(16) u16 Vs[64][68];
  __shared__ __align__(16) u16 Ps[4][16][68];
  const int t = threadIdx.x, w = t >> 6, l = t & 63;
  const int l4 = l >> 4, l15 = l & 15;
  const int bid = blockIdx.x;              // 2048 linear
  const int s   = 31 - (bid >> 6);         // q-segment, longest (s=31) first
  const int bh  = bid & 63;                // bh%8 == bid%8 == XCD id (K/V hot in that L2)
  const int b = bh >> 4, h = bh & 15;
  const int q0 = s * 64 + w * 16;          // this wave's 16 q-rows
  const u16* Qb = Qh + (size_t)bh * 2048 * 64;
  const u16* Kb = Kh + (size_t)bh * 2048 * 64;
  const u16* Vb = Vt + (size_t)bh * 64 * 2048;

  bf16x8 qf[2];
#pragma unroll
  for (int ks = 0; ks < 2; ++ks)
    qf[ks] = *(const bf16x8*)(Qb + (size_t)(q0 + l15) * 64 + ks * 32 + l4 * 8);

  f32x4 o[4];
#pragma unroll
  for (int nd = 0; nd < 4; ++nd) o[nd] = f32x4{0.f, 0.f, 0.f, 0.f};
  float lsum = 0.f;                        // per-lane partial row sum (reduced in epilogue)

  const int sr = t >> 3;          // 0..31
  const int scol = (t & 7) * 8;   // 0..56
  const int nkv = s + 1;

  // prologue: tile 0 -> regs
  u16x8 rk0 = *(const u16x8*)(Kb + (size_t)sr * 64 + scol);
  u16x8 rk1 = *(const u16x8*)(Kb + (size_t)(sr + 32) * 64 + scol);
  u16x8 rv0 = *(const u16x8*)(Vb + (size_t)sr * 2048 + scol);
  u16x8 rv1 = *(const u16x8*)(Vb + (size_t)(sr + 32) * 2048 + scol);

  for (int kv = 0; kv < nkv; ++kv) {
    const int kv0 = kv * 64;
    __syncthreads();                       // prev compute done reading LDS
    *(u16x8*)&Ks[sr][scol]      = rk0;
    *(u16x8*)&Ks[sr + 32][scol] = rk1;
    *(u16x8*)&Vs[sr][scol]      = rv0;     // Vs[d][key]
    *(u16x8*)&Vs[sr + 32][scol] = rv1;
    __syncthreads();
    if (kv + 1 < nkv) {                    // next tile -> regs (1-iter-early prefetch, T14)
      const int n0 = kv0 + 64;
      rk0 = *(const u16x8*)(Kb + (size_t)(n0 + sr) * 64 + scol);
      rk1 = *(const u16x8*)(Kb + (size_t)(n0 + sr + 32) * 64 + scol);
      rv0 = *(const u16x8*)(Vb + (size_t)sr * 2048 + n0 + scol);
      rv1 = *(const u16x8*)(Vb + (size_t)(sr + 32) * 2048 + n0 + scol);
    }

    // SCORE: swapped QK^T -> sfr[n][r] = S[key=kv0+n*16+l4*4+r][q=q0+l15]
    f32x4 sfr[4];
    __builtin_amdgcn_s_setprio(1);
#pragma unroll
    for (int n = 0; n < 4; ++n) {
      bf16x8 kf0 = *(const bf16x8*)&Ks[n * 16 + l15][l4 * 8];
      bf16x8 kf1 = *(const bf16x8*)&Ks[n * 16 + l15][32 + l4 * 8];
      f32x4 a = f32x4{0.f, 0.f, 0.f, 0.f};
      a = __builtin_amdgcn_mfma_f32_16x16x32_bf16(kf0, qf[0], a, 0, 0, 0);
      a = __builtin_amdgcn_mfma_f32_16x16x32_bf16(kf1, qf[1], a, 0, 0, 0);
      sfr[n] = a;
    }
    __builtin_amdgcn_s_setprio(0);
    if (kv == s) {                         // diagonal tile: mask key > q
      const int q = q0 + l15;
#pragma unroll
      for (int n = 0; n < 4; ++n)
#pragma unroll
        for (int r = 0; r < 4; ++r)
          if (kv0 + n * 16 + l4 * 4 + r > q) sfr[n][r] = -1e30f;
    }
    float rs = 0.f;
#pragma unroll
    for (int n = 0; n < 4; ++n) {
#pragma unroll
      for (int r = 0; r < 4; ++r) {
        const float pv = exp2fast(sfr[n][r]);   // no max shift (bounded log2 scores)
        sfr[n][r] = pv; rs += pv;
      }
      u16x4 pk = {f2bf(sfr[n][0]), f2bf(sfr[n][1]), f2bf(sfr[n][2]), f2bf(sfr[n][3])};
      *(u16x4*)&Ps[w][l15][n * 16 + l4 * 4] = pk;
    }
    lsum += rs;

    // PV
    bf16x8 vfr[4][2];
#pragma unroll
    for (int nd = 0; nd < 4; ++nd) {
      vfr[nd][0] = *(const bf16x8*)&Vs[nd * 16 + l15][l4 * 8];
      vfr[nd][1] = *(const bf16x8*)&Vs[nd * 16 + l15][32 + l4 * 8];
    }
    bf16x8 pf0 = *(const bf16x8*)&Ps[w][l15][l4 * 8];
    bf16x8 pf1 = *(const bf16x8*)&Ps[w][l15][32 + l4 * 8];
    __builtin_amdgcn_s_setprio(1);
#pragma unroll
    for (int nd = 0; nd < 4; ++nd) {
      o[nd] = __builtin_amdgcn_mfma_f32_16x16x32_bf16(pf0, vfr[nd][0], o[nd], 0, 0, 0);
      o[nd] = __builtin_amdgcn_mfma_f32_16x16x32_bf16(pf1, vfr[nd][1], o[nd], 0, 0, 0);
    }
    __builtin_amdgcn_s_setprio(0);
  }

  // epilogue: reduce lsum across the 4 lane-groups, broadcast 1/l into o-layout, write Y
  lsum += __shfl_xor(lsum, 16);
  lsum += __shfl_xor(lsum, 32);
  const float li = 1.0f / lsum;
  float lb[4];
#pragma unroll
  for (int r = 0; r < 4; ++r) lb[r] = __shfl(li, (l & 48) | (l4 * 4 + r));
#pragma unroll
  for (int r = 0; r < 4; ++r) {
    const size_t row = (size_t)b * 2048 + q0 + l4 * 4 + r;
#pragma unroll
    for (int nd = 0; nd < 4; ++nd)
      Y[row * 1024 + h * 64 + nd * 16 + l15] = f2bf(o[nd][r] * lb[r]);
  }
}

extern "C" void kernel_launch(void* const* d_in, const int* in_sizes, int n_in,
                              void* d_out, int out_size, void* d_ws, size_t ws_size,
                              hipStream_t stream) {
  const float* x    = (const float*)d_in[0];   // 4*2048*1024
  const float* wqkv = (const float*)d_in[1];   // 3072*1024
  const float* wout = (const float*)d_in[2];   // 1024*1024
  float* out = (float*)d_out;                  // 8192*1024 fp32
  char* ws = (char*)d_ws;

  u16* x_bf    = (u16*)(ws);               // 16 MiB (reused as Y after gemm_qkv)
  u16* Y       = x_bf;
  u16* wqkv_bf = (u16*)(ws + 16777216);    // 6 MiB
  u16* wout_bf = (u16*)(ws + 23068672);    // 2 MiB
  float2* tab  = (float2*)(ws + 25165824); // 512 KiB (rope cos/sin table)
  u16* Qh      = (u16*)(ws + 75497472);    // 16 MiB
  u16* Kh      = (u16*)(ws + 92274688);    // 16 MiB
  u16* Vt      = (u16*)(ws + 109051904);   // 16 MiB

  cvt3_kernel<<<12544, 256, 0, stream>>>(x, x_bf, wqkv, wqkv_bf, wout, wout_bf, tab);
  gemm_qkv<<<dim3(24, 64), 256, 0, stream>>>(x_bf, wqkv_bf, tab, Qh, Kh, Vt);
  attn_kernel<<<2048, 256, 0, stream>>>(Qh, Kh, Vt, Y);
  gemm_bt<false><<<dim3(8, 64), 256, 0, stream>>>(Y, wout_bf, out, 8192, 1024, 1024);
}